// Round 23
// baseline (333.036 us; speedup 1.0000x reference)
//
#include <hip/hip_runtime.h>
#include <math.h>

#define NN 50000
#define NBB 256
#define DD 128
#define FF 16
#define EE 800000
#define RR 15
#define EPSV 1e-7f
#define CSPACE (5.0f/14.0f)
#define NBLK 782   // ceil(NN/64)
#define NGA 782    // gather blocks: 64 nodes/block, half-split moments

__device__ __forceinline__ float lrelu(float x){ return x >= 0.f ? x : 0.01f*x; }
__device__ __forceinline__ float sigmoidf_(float x){ return 1.f/(1.f+expf(-x)); }

typedef __bf16 bf16x8 __attribute__((ext_vector_type(8)));
typedef float f32x4 __attribute__((ext_vector_type(4)));

__device__ __forceinline__ unsigned short f2bf(float x){
    union { float f; unsigned int u; } a; a.f = x;
    unsigned int r = (a.u + 0x7fffu + ((a.u >> 16) & 1u)) >> 16;
    return (unsigned short)r;
}
__device__ __forceinline__ unsigned int pack2(float a, float b){
    return (unsigned int)f2bf(a) | ((unsigned int)f2bf(b) << 16);
}
__device__ __forceinline__ float bf2f(unsigned short v){
    union { unsigned int u; float f; } a; a.u = ((unsigned int)v) << 16; return a.f;
}
__device__ __forceinline__ bf16x8 ld8(const unsigned short* p){
    union { uint4 u; bf16x8 b; } x; x.u = *(const uint4*)p; return x.b;
}

// ---------------- pack weights + zero deg + kv projection (blocks >= 384) ----------------
__global__ __launch_bounds__(256) void k_prep(
    const float* __restrict__ Wih, const float* __restrict__ Whh,
    const float* __restrict__ Wq,
    const float* __restrict__ phi1W, const float* __restrict__ phi2W,
    const float* __restrict__ phi3W,
    const float* __restrict__ Wr1, const float* __restrict__ br1,
    const float* __restrict__ hB, const float* __restrict__ Wk,
    const float* __restrict__ Wv, const float* __restrict__ bv,
    unsigned short* __restrict__ pWih, unsigned short* __restrict__ pWhh,
    unsigned short* __restrict__ pWq,
    unsigned short* __restrict__ pPhi1, unsigned short* __restrict__ pPhi2,
    unsigned short* __restrict__ pPhi3, unsigned short* __restrict__ pWr1,
    unsigned short* __restrict__ pKK, unsigned short* __restrict__ pVV,
    int* __restrict__ deg)
{
    if (blockIdx.x >= 384){
        __shared__ float sB[2][DD];
        int sub = threadIdx.x >> 7, j = threadIdx.x & 127;
        int b = (blockIdx.x - 384)*2 + sub;
        sB[sub][j] = hB[(size_t)b*DD + j];
        __syncthreads();
        float ak = 0.f, av = bv[j];
        for (int i = 0; i < DD; ++i){
            float h = sB[sub][i];
            ak += h*Wk[i*DD+j];
            av += h*Wv[i*DD+j];
        }
        {
            int c = b>>4, lr = b&15, kt = j>>5, lg = (j>>3)&3, e = j&7;
            pKK[((c*4+kt)*64 + lg*16 + lr)*8 + e] = f2bf(lrelu(ak));
        }
        {
            int kt = b>>5, lg = (b>>3)&3, e = b&7, c = j>>4, lr = j&15;
            pVV[((c*8+kt)*64 + lg*16 + lr)*8 + e] = f2bf(av);
        }
        return;
    }
    int i = blockIdx.x*256 + threadIdx.x;
    if (i < NN) deg[i] = 0;
    if (i < 3*8*8*64*8){
        int e = i&7, l=(i>>3)&63, kt=(i>>9)&7, c=(i>>12)&7, q=i>>15;
        int row = q*128 + c*16 + (l&15);
        int k = kt*32 + (l>>4)*8 + e;
        pWih[i] = f2bf(Wih[row*256 + k]);
    }
    if (i < 3*8*4*64*8){
        int e = i&7, l=(i>>3)&63, kt=(i>>9)&3, c=(i>>11)&7, q=i>>14;
        int row = q*128 + c*16 + (l&15);
        int k = kt*32 + (l>>4)*8 + e;
        pWhh[i] = f2bf(Whh[row*128 + k]);
    }
    if (i < 8*4*64*8){
        int e = i&7, l=(i>>3)&63, kt=(i>>9)&3, c=(i>>11)&7;
        pWq[i] = f2bf(Wq[(kt*32 + (l>>4)*8 + e)*DD + c*16 + (l&15)]);
    }
    if (i < 8*5*64*8){
        int e = i&7, l=(i>>3)&63;
        int t = i>>9;
        int kt = t%5, c = t/5;
        int k = kt*32 + (l>>4)*8 + e;
        int col = c*16 + (l&15);
        pPhi1[i] = f2bf(k < 144 ? phi1W[k*DD + col] : 0.f);
    }
    if (i < 5*64*8){
        int e = i&7, l=(i>>3)&63, kt = i>>9;
        int k = kt*32 + (l>>4)*8 + e;
        int col = l&15;
        pPhi2[i] = f2bf(k < 144 ? phi2W[k*FF + col] : 0.f);
    }
    if (i < 4*64*8){
        int e = i&7, l=(i>>3)&63, kt = i>>9;
        int k = kt*32 + (l>>4)*8 + e;
        int col = l&15;
        pPhi3[i] = f2bf(phi3W[k*FF + col]);
    }
    if (i < 8*64*8){
        int e = i&7, l=(i>>3)&63, c = i>>9;
        int col = c*16 + (l&15);
        int k = (l>>4)*8 + e;
        float v = 0.f;
        if (k == 0) v = br1[col];
        else if (k < 16) v = Wr1[(k-1)*DD + col];
        pWr1[i] = f2bf(v);
    }
}

// ---------------- fused per-node features; publishes hA bf16 swizzled image ----------------
__global__ __launch_bounds__(512) void k_node(
    const float* __restrict__ hA, const float* __restrict__ vA,
    const float* __restrict__ vn1W, const float* __restrict__ vn1U,
    const float* __restrict__ vn2W, const float* __restrict__ vn2U,
    const float* __restrict__ vn3W, const float* __restrict__ vn3U,
    const unsigned short* __restrict__ pPhi1, const float* __restrict__ phi1b,
    const unsigned short* __restrict__ pPhi2, const float* __restrict__ phi2b,
    const unsigned short* __restrict__ pPhi3, const float* __restrict__ phi3b,
    unsigned short* __restrict__ hpB, float* __restrict__ hppO, float* __restrict__ vpO,
    unsigned short* __restrict__ hAB)
{
    __shared__ unsigned short sH[64*128];
    __shared__ unsigned short sE[64*64];
    __shared__ float sVA[64*48];
    __shared__ float sO3[64*16*3];
    __shared__ float sW[6*256];
    int tid = threadIdx.x;
    int n0 = blockIdx.x*64;

    #pragma unroll
    for (int it = 0; it < 2; ++it){
        int c = tid + it*512;
        int row = c >> 4, cb = c & 15;
        int gn = n0 + row; if (gn > NN-1) gn = NN-1;
        const float* p = hA + (size_t)gn*DD + cb*8;
        float4 f0 = *(const float4*)p;
        float4 f1 = *(const float4*)(p+4);
        uint4 u;
        u.x = pack2(f0.x,f0.y); u.y = pack2(f0.z,f0.w);
        u.z = pack2(f1.x,f1.y); u.w = pack2(f1.z,f1.w);
        *(uint4*)&sH[row*128 + ((cb ^ (row&7))*8)] = u;
    }
    #pragma unroll
    for (int it = 0; it < 6; ++it){
        int i = tid + it*512;
        int row = i/48, cc = i%48;
        int gn = n0 + row; if (gn > NN-1) gn = NN-1;
        sVA[i] = vA[(size_t)gn*48 + cc];
    }
    #pragma unroll
    for (int it = 0; it < 3; ++it){
        int i = tid + it*512;
        float v;
        if      (i <  256) v = vn1W[i];
        else if (i <  512) v = vn1U[i-256];
        else if (i <  768) v = vn2W[i-512];
        else if (i < 1024) v = vn2U[i-768];
        else if (i < 1280) v = vn3W[i-1024];
        else               v = vn3U[i-1280];
        sW[i] = v;
    }
    {
        uint2* z = (uint2*)sE;
        z[tid] = make_uint2(0u,0u);
        z[tid+512] = make_uint2(0u,0u);
    }
    __syncthreads();

    #pragma unroll
    for (int it = 0; it < 2; ++it){
        int i = tid + it*512;
        ((uint4*)hAB)[(size_t)blockIdx.x*1024 + i] = ((const uint4*)sH)[i];
    }

    #pragma unroll
    for (int it = 0; it < 2; ++it){
        int item = tid + it*512;
        int nl = item >> 4, g = item & 15;
        const float* v = &sVA[nl*48];
        float q0[3]={0,0,0}, q1[3]={0,0,0}, q2[3]={0,0,0};
        float c0[3]={0,0,0}, c1[3]={0,0,0}, c2[3]={0,0,0};
        #pragma unroll
        for (int ff = 0; ff < FF; ++ff){
            int fi = (ff + g) & 15;
            float v0 = v[fi*3], v1 = v[fi*3+1], v2 = v[fi*3+2];
            #pragma unroll
            for (int m = 0; m < 3; ++m){
                float w = sW[m*512 + g*16 + fi];
                float u = sW[m*512 + 256 + g*16 + fi];
                q0[m] += w*v0; q1[m] += w*v1; q2[m] += w*v2;
                c0[m] += u*v0; c1[m] += u*v1; c2[m] += u*v2;
            }
        }
        #pragma unroll
        for (int m = 0; m < 3; ++m){
            float dot = q0[m]*c0[m] + q1[m]*c1[m] + q2[m]*c2[m];
            float ksq = c0[m]*c0[m] + c1[m]*c1[m] + c2[m]*c2[m] + EPSV;
            float s = dot >= 0.f ? 0.f : dot/ksq;
            float o0 = q0[m]-s*c0[m], o1 = q1[m]-s*c1[m], o2 = q2[m]-s*c2[m];
            if (m < 2){
                float nr = sqrtf(o0*o0+o1*o1+o2*o2) + EPSV;
                int col = (m==0) ? g : (32+g);
                int cb = col>>3;
                sE[nl*64 + ((cb ^ (nl&7))*8) + (col&7)] = f2bf(nr);
            } else {
                float* o = &sO3[(nl*16+g)*3];
                o[0]=o0; o[1]=o1; o[2]=o2;
            }
        }
    }
    __syncthreads();

    int wv = tid>>6, l = tid&63, lr = l&15, lg = l>>4;

    f32x4 a1[4];
    #pragma unroll
    for (int rt = 0; rt < 4; ++rt) a1[rt] = (f32x4){0.f,0.f,0.f,0.f};
    for (int kt = 0; kt < 4; ++kt){
        bf16x8 b = ld8(pPhi1 + ((size_t)(wv*5+kt)*64 + l)*8);
        #pragma unroll
        for (int rt = 0; rt < 4; ++rt){
            int row = rt*16 + lr;
            bf16x8 a = ld8(&sH[row*128 + (((kt*4+lg) ^ (row&7))*8)]);
            a1[rt] = __builtin_amdgcn_mfma_f32_16x16x32_bf16(a, b, a1[rt], 0, 0, 0);
        }
    }
    {
        bf16x8 b = ld8(pPhi1 + ((size_t)(wv*5+4)*64 + l)*8);
        #pragma unroll
        for (int rt = 0; rt < 4; ++rt){
            int row = rt*16 + lr;
            bf16x8 a = ld8(&sE[row*64 + ((lg ^ (row&7))*8)]);
            a1[rt] = __builtin_amdgcn_mfma_f32_16x16x32_bf16(a, b, a1[rt], 0, 0, 0);
        }
    }
    f32x4 a23 = (f32x4){0.f,0.f,0.f,0.f};
    if (wv < 4){
        int row = wv*16 + lr;
        for (int kt = 0; kt < 4; ++kt){
            bf16x8 b = ld8(pPhi3 + ((size_t)kt*64 + l)*8);
            bf16x8 a = ld8(&sH[row*128 + (((kt*4+lg) ^ (row&7))*8)]);
            a23 = __builtin_amdgcn_mfma_f32_16x16x32_bf16(a, b, a23, 0, 0, 0);
        }
    } else {
        int row = (wv-4)*16 + lr;
        for (int kt = 0; kt < 4; ++kt){
            bf16x8 b = ld8(pPhi2 + ((size_t)kt*64 + l)*8);
            bf16x8 a = ld8(&sH[row*128 + (((kt*4+lg) ^ (row&7))*8)]);
            a23 = __builtin_amdgcn_mfma_f32_16x16x32_bf16(a, b, a23, 0, 0, 0);
        }
        {
            bf16x8 b = ld8(pPhi2 + ((size_t)4*64 + l)*8);
            bf16x8 a = ld8(&sE[row*64 + (((4+lg) ^ (row&7))*8)]);
            a23 = __builtin_amdgcn_mfma_f32_16x16x32_bf16(a, b, a23, 0, 0, 0);
        }
    }

    {
        int col = wv*16 + lr;
        float b1 = phi1b[col];
        #pragma unroll
        for (int rt = 0; rt < 4; ++rt){
            #pragma unroll
            for (int r4 = 0; r4 < 4; ++r4){
                int n = n0 + rt*16 + lg*4 + r4;
                if (n < NN) hpB[(size_t)n*DD + col] = f2bf(lrelu(a1[rt][r4] + b1));
            }
        }
    }
    if (wv < 4){
        float b3 = phi3b[lr];
        #pragma unroll
        for (int r4 = 0; r4 < 4; ++r4){
            int nl = wv*16 + lg*4 + r4;
            int n = n0 + nl;
            float gate = lrelu(a23[r4] + b3);
            if (n < NN){
                const float* o = &sO3[(nl*16+lr)*3];
                float* vo = vpO + (size_t)n*48 + lr*3;
                vo[0] = o[0]*gate; vo[1] = o[1]*gate; vo[2] = o[2]*gate;
            }
        }
    } else {
        float b2 = phi2b[lr];
        #pragma unroll
        for (int r4 = 0; r4 < 4; ++r4){
            int nl = (wv-4)*16 + lg*4 + r4;
            int n = n0 + nl;
            if (n < NN) hppO[(size_t)n*FF + lr] = lrelu(a23[r4] + b2);
        }
    }
}

// ---------------- edge phase ----------------
__global__ __launch_bounds__(256) void k_hist(const int* __restrict__ dst, int* __restrict__ deg){
    int e = blockIdx.x*256 + threadIdx.x;
    if (e < EE) atomicAdd(&deg[dst[e]], 1);
}

__global__ __launch_bounds__(256) void k_scan1(const int* __restrict__ deg,
                                               int* __restrict__ excl, int* __restrict__ bsum){
    __shared__ int s[256];
    int tid = threadIdx.x;
    int i = blockIdx.x*256 + tid;
    int v = (i < NN) ? deg[i] : 0;
    s[tid] = v;
    __syncthreads();
    for (int o = 1; o < 256; o <<= 1){
        int t = 0;
        if (tid >= o) t = s[tid-o];
        __syncthreads();
        if (tid >= o) s[tid] += t;
        __syncthreads();
    }
    if (i < NN) excl[i] = s[tid] - v;
    if (tid == 255) bsum[blockIdx.x] = s[255];
}

__global__ __launch_bounds__(256) void k_scan23(const int* __restrict__ excl,
                                                const int* __restrict__ bsum, int nb,
                                                int* __restrict__ start, int* __restrict__ cursor){
    __shared__ int s[256];
    int tid = threadIdx.x;
    int v = (tid < nb) ? bsum[tid] : 0;
    s[tid] = v;
    __syncthreads();
    for (int o = 1; o < 256; o <<= 1){
        int t = 0;
        if (tid >= o) t = s[tid-o];
        __syncthreads();
        if (tid >= o) s[tid] += t;
        __syncthreads();
    }
    int boff = (blockIdx.x == 0) ? 0 : s[blockIdx.x - 1];
    int i = blockIdx.x*256 + tid;
    if (i < NN){
        int st = excl[i] + boff;
        start[i] = st;
        cursor[i] = st;
    }
    if (i == 0) start[NN] = EE;
}

__global__ __launch_bounds__(256) void k_scatter(const int* __restrict__ src,
                                                 const int* __restrict__ dst,
                                                 int* __restrict__ cursor, int* __restrict__ esrc){
    int e = blockIdx.x*256 + threadIdx.x;
    if (e >= EE) return;
    int pos = atomicAdd(&cursor[dst[e]], 1);
    esrc[pos] = src[e];
}

// ---------------- MERGED: gather (blocks < NGA, wave-half moment split) + attention ----------------
// Gather: 64 nodes/block. Threads 0-255 accumulate moments 0..30 (31 regs),
// threads 256-511 accumulate moments 31..63 (33 regs). Disjoint branches ->
// register allocator overlaps the arrays (peak ~50 VGPR, no spill); branch is
// wave-uniform -> no divergence serialization. Each edge walked by 2 lanes.
__global__ __launch_bounds__(512) void k_ga_attn(
    const int* __restrict__ start, const int* __restrict__ esrc,
    const float* __restrict__ xA, const float* __restrict__ rbf_k,
    float* __restrict__ acc,
    const unsigned short* __restrict__ hAB, const unsigned short* __restrict__ pWq,
    const unsigned short* __restrict__ pKK, const unsigned short* __restrict__ pVV,
    const float* __restrict__ mask, unsigned short* __restrict__ attnB)
{
    __shared__ __align__(16) unsigned char smem[33792];
    int tid = threadIdx.x;
    if (blockIdx.x < NGA){
        int half = tid >> 8;           // wave-uniform (waves 0-3 vs 4-7)
        int t = tid & 255;
        int n = blockIdx.x*64 + (t >> 2);
        int sub = t & 3;
        if (n >= NN) return;
        float kc = rbf_k[0];
        float xd0 = xA[n*3+0], xd1 = xA[n*3+1], xd2 = xA[n*3+2];
        int b0 = start[n], b1 = start[n+1];
        float* accn = acc + (size_t)n*64;
        if (half == 0){
            // moments 0..30: cnt, rbf[0..14], r[0..2], rbf[q]*r for q=0..3
            float a[31];
            #pragma unroll
            for (int i = 0; i < 31; ++i) a[i] = 0.f;
            for (int i = b0 + sub; i < b1; i += 4){
                int s = esrc[i];
                float r0 = xA[s*3+0]-xd0, r1 = xA[s*3+1]-xd1, r2 = xA[s*3+2]-xd2;
                float rn = sqrtf(r0*r0+r1*r1+r2*r2);
                a[0] += 1.f;
                a[16] += r0; a[17] += r1; a[18] += r2;
                #pragma unroll
                for (int q = 0; q < RR; ++q){
                    float df = rn - (float)q*CSPACE;
                    float rb = expf(-df*df*kc);
                    a[1+q] += rb;
                    if (q < 4){
                        a[19+q*3+0] += rb*r0;
                        a[19+q*3+1] += rb*r1;
                        a[19+q*3+2] += rb*r2;
                    }
                }
            }
            #pragma unroll
            for (int i = 0; i < 31; ++i){
                a[i] += __shfl_xor(a[i], 1);
                a[i] += __shfl_xor(a[i], 2);
            }
            for (int i = sub; i < 31; i += 4) accn[i] = a[i];
        } else {
            // moments 31..63: rbf[q]*r for q=4..14
            float a[33];
            #pragma unroll
            for (int i = 0; i < 33; ++i) a[i] = 0.f;
            for (int i = b0 + sub; i < b1; i += 4){
                int s = esrc[i];
                float r0 = xA[s*3+0]-xd0, r1 = xA[s*3+1]-xd1, r2 = xA[s*3+2]-xd2;
                float rn = sqrtf(r0*r0+r1*r1+r2*r2);
                #pragma unroll
                for (int q = 4; q < RR; ++q){
                    float df = rn - (float)q*CSPACE;
                    float rb = expf(-df*df*kc);
                    int j = (q-4)*3;
                    a[j+0] += rb*r0;
                    a[j+1] += rb*r1;
                    a[j+2] += rb*r2;
                }
            }
            #pragma unroll
            for (int i = 0; i < 33; ++i){
                a[i] += __shfl_xor(a[i], 1);
                a[i] += __shfl_xor(a[i], 2);
            }
            for (int i = sub; i < 33; i += 4) accn[31+i] = a[i];
        }
        return;
    }
    int ab = blockIdx.x - NGA;
    unsigned short* sU = (unsigned short*)smem;
    float* sMx = (float*)(smem + 32768);
    float* sSm = (float*)(smem + 33280);
    unsigned short* sX = sU;
    unsigned short* sQ = sU + 64*128;
    unsigned short* sP = sU;
    unsigned short* sImg = sU;
    int n0 = ab*64;

    #pragma unroll
    for (int it = 0; it < 2; ++it){
        int i = tid + it*512;
        ((uint4*)sX)[i] = ((const uint4*)hAB)[(size_t)ab*1024 + i];
    }
    __syncthreads();

    int wv = tid>>6, l = tid&63, lr = l&15, lg = l>>4;
    int rw = wv>>1, chh = wv&1;
    int rowA = rw*16 + lr;

    {
        f32x4 q[4];
        #pragma unroll
        for (int c = 0; c < 4; ++c) q[c] = (f32x4){0.f,0.f,0.f,0.f};
        for (int kt = 0; kt < 4; ++kt){
            bf16x8 a = ld8(&sX[rowA*128 + (((kt*4+lg) ^ (rowA&7))*8)]);
            #pragma unroll
            for (int c = 0; c < 4; ++c){
                bf16x8 b = ld8(pWq + (size_t)(((chh*4+c)*4 + kt)*512) + l*8);
                q[c] = __builtin_amdgcn_mfma_f32_16x16x32_bf16(a, b, q[c], 0, 0, 0);
            }
        }
        __syncthreads();
        #pragma unroll
        for (int c = 0; c < 4; ++c)
        #pragma unroll
        for (int r4 = 0; r4 < 4; ++r4){
            int row = rw*16 + lg*4 + r4;
            int col = chh*64 + c*16 + lr;
            int cb = col>>3;
            sQ[row*128 + ((cb ^ (row&7))*8) + (col&7)] = f2bf(lrelu(q[c][r4]));
        }
    }
    __syncthreads();

    f32x4 S[8];
    #pragma unroll
    for (int cl = 0; cl < 8; ++cl) S[cl] = (f32x4){0.f,0.f,0.f,0.f};
    for (int kt = 0; kt < 4; ++kt){
        bf16x8 a = ld8(&sQ[rowA*128 + (((kt*4+lg) ^ (rowA&7))*8)]);
        #pragma unroll
        for (int cl = 0; cl < 8; ++cl){
            bf16x8 b = ld8(pKK + (size_t)(((chh*8+cl)*4 + kt)*512) + l*8);
            S[cl] = __builtin_amdgcn_mfma_f32_16x16x32_bf16(a, b, S[cl], 0, 0, 0);
        }
    }
    float den[4];
    #pragma unroll
    for (int r4 = 0; r4 < 4; ++r4){
        int row = rw*16 + lg*4 + r4;
        int gn = n0 + row; if (gn > NN-1) gn = NN-1;
        float mx = -1e30f;
        #pragma unroll
        for (int cl = 0; cl < 8; ++cl){
            int col = chh*128 + cl*16 + lr;
            float m = mask[(size_t)gn*NBB + col];
            float s = m*S[cl][r4] - 1000.f*(1.f-m);
            S[cl][r4] = s;
            mx = fmaxf(mx, s);
        }
        mx = fmaxf(mx, __shfl_xor(mx, 1));
        mx = fmaxf(mx, __shfl_xor(mx, 2));
        mx = fmaxf(mx, __shfl_xor(mx, 4));
        mx = fmaxf(mx, __shfl_xor(mx, 8));
        if (lr == 0) sMx[row*2+chh] = mx;
    }
    __syncthreads();
    #pragma unroll
    for (int r4 = 0; r4 < 4; ++r4){
        int row = rw*16 + lg*4 + r4;
        float m = fmaxf(sMx[row*2+0], sMx[row*2+1]);
        float sm = 0.f;
        #pragma unroll
        for (int cl = 0; cl < 8; ++cl){
            float p = expf(S[cl][r4] - m);
            S[cl][r4] = p;
            sm += p;
        }
        sm += __shfl_xor(sm, 1);
        sm += __shfl_xor(sm, 2);
        sm += __shfl_xor(sm, 4);
        sm += __shfl_xor(sm, 8);
        if (lr == 0) sSm[row*2+chh] = sm;
    }
    __syncthreads();
    #pragma unroll
    for (int r4 = 0; r4 < 4; ++r4){
        int row = rw*16 + lg*4 + r4;
        den[r4] = sSm[row*2+0] + sSm[row*2+1];
    }
    #pragma unroll
    for (int cl = 0; cl < 8; ++cl)
    #pragma unroll
    for (int r4 = 0; r4 < 4; ++r4){
        int row = rw*16 + lg*4 + r4;
        int col = chh*128 + cl*16 + lr;
        int cb = col>>3;
        sP[row*256 + ((cb ^ (row&7))*8) + (col&7)] = f2bf(S[cl][r4]);
    }
    __syncthreads();

    f32x4 O[4];
    #pragma unroll
    for (int c = 0; c < 4; ++c) O[c] = (f32x4){0.f,0.f,0.f,0.f};
    for (int kt = 0; kt < 8; ++kt){
        bf16x8 a = ld8(&sP[rowA*256 + (((kt*4+lg) ^ (rowA&7))*8)]);
        #pragma unroll
        for (int c = 0; c < 4; ++c){
            bf16x8 b = ld8(pVV + (size_t)(((chh*4+c)*8 + kt)*512) + l*8);
            O[c] = __builtin_amdgcn_mfma_f32_16x16x32_bf16(a, b, O[c], 0, 0, 0);
        }
    }
    __syncthreads();
    #pragma unroll
    for (int c = 0; c < 4; ++c)
    #pragma unroll
    for (int r4 = 0; r4 < 4; ++r4){
        int row = rw*16 + lg*4 + r4;
        int col = chh*64 + c*16 + lr;
        sImg[row*128 + (((col>>3) ^ (row&7))*8) + (col&7)] = f2bf(O[c][r4] / den[r4]);
    }
    __syncthreads();
    #pragma unroll
    for (int it = 0; it < 2; ++it){
        int i = tid + it*512;
        ((uint4*)attnB)[(size_t)ab*1024 + i] = ((const uint4*)sImg)[i];
    }
}

// ---------------- GRU via bf16 MFMA; both input halves = verbatim image copies ----------------
__global__ __launch_bounds__(512) void k_gru_mfma(
    const unsigned short* __restrict__ hAB, const unsigned short* __restrict__ attnB,
    const unsigned short* __restrict__ hpB, const float* __restrict__ acc,
    const unsigned short* __restrict__ pWr1,
    const unsigned short* __restrict__ pWih, const unsigned short* __restrict__ pWhh,
    const float* __restrict__ bih, const float* __restrict__ bhh,
    float* __restrict__ outNode)
{
    __shared__ unsigned short sX[64*256];   // 32KB
    __shared__ unsigned short sGm[64*128];  // 16KB; head doubles as sM
    __shared__ float sCnt[64];
    unsigned short* sM = sGm;
    int tid = threadIdx.x;
    int n0 = blockIdx.x*64;

    #pragma unroll
    for (int it = 0; it < 2; ++it){
        int i = tid + it*512;
        uint4 v = ((const uint4*)hAB)[(size_t)blockIdx.x*1024 + i];
        int row = i >> 4, p = i & 15;
        *(uint4*)&sX[row*256 + p*8] = v;
    }
    #pragma unroll
    for (int it = 0; it < 2; ++it){
        int i = tid + it*512;
        uint4 v = ((const uint4*)attnB)[(size_t)blockIdx.x*1024 + i];
        int row = i >> 4, p = i & 15;
        *(uint4*)&sX[row*256 + 128 + p*8] = v;
    }
    #pragma unroll
    for (int it = 0; it < 4; ++it){
        int i = tid + it*512;
        int row = i >> 5, k = i & 31;
        int gn = n0 + row; if (gn > NN-1) gn = NN-1;
        float v = (k < 16) ? acc[(size_t)gn*64 + k] : 0.f;
        sM[row*40 + k] = f2bf(v);
        if (k == 0) sCnt[row] = v;
    }
    __syncthreads();

    int wv = tid >> 6, l = tid & 63;
    int lr = l & 15, lg = l >> 4;
    int col = wv*16 + lr;

    {
        f32x4 sv[4];
        #pragma unroll
        for (int rt = 0; rt < 4; ++rt) sv[rt] = (f32x4){0.f,0.f,0.f,0.f};
        bf16x8 b = ld8(pWr1 + (size_t)wv*512 + l*8);
        #pragma unroll
        for (int rt = 0; rt < 4; ++rt){
            int row = rt*16 + lr;
            bf16x8 a = ld8(&sM[row*40 + lg*8]);
            sv[rt] = __builtin_amdgcn_mfma_f32_16x16x32_bf16(a, b, sv[rt], 0, 0, 0);
        }
        __syncthreads();
        #pragma unroll
        for (int rt = 0; rt < 4; ++rt){
            #pragma unroll
            for (int r4 = 0; r4 < 4; ++r4){
                int row = rt*16 + lg*4 + r4;
                int gn = n0 + row; if (gn > NN-1) gn = NN-1;
                float cnt = sCnt[row];
                float den = fmaxf(cnt, 1.f);
                float g = bf2f(hpB[(size_t)gn*DD + col]) * sv[rt][r4] / den;
                sGm[row*128 + (((col>>3) ^ (row&7))*8) + (col&7)] = f2bf(g);
            }
        }
    }
    __syncthreads();

    f32x4 aR[4], aZ[4], aNI[4], aNH[4];
    #pragma unroll
    for (int rt = 0; rt < 4; ++rt){
        aR[rt] = (f32x4){0.f,0.f,0.f,0.f};
        aZ[rt] = (f32x4){0.f,0.f,0.f,0.f};
        aNI[rt] = (f32x4){0.f,0.f,0.f,0.f};
        aNH[rt] = (f32x4){0.f,0.f,0.f,0.f};
    }
    const unsigned short* bR = pWih + ((size_t)(0*8 + wv)*8)*512 + l*8;
    const unsigned short* bZ = pWih + ((size_t)(1*8 + wv)*8)*512 + l*8;
    const unsigned short* bN = pWih + ((size_t)(2*8 + wv)*8)*512 + l*8;
    for (int kt = 0; kt < 8; ++kt){
        bf16x8 br_ = ld8(bR + kt*512);
        bf16x8 bz_ = ld8(bZ + kt*512);
        bf16x8 bn_ = ld8(bN + kt*512);
        #pragma unroll
        for (int rt = 0; rt < 4; ++rt){
            int rowA = rt*16 + lr;
            bf16x8 a = ld8(&sX[rowA*256 + (((kt*4 + lg) ^ (rowA&7))*8)]);
            aR[rt]  = __builtin_amdgcn_mfma_f32_16x16x32_bf16(a, br_, aR[rt], 0, 0, 0);
            aZ[rt]  = __builtin_amdgcn_mfma_f32_16x16x32_bf16(a, bz_, aZ[rt], 0, 0, 0);
            aNI[rt] = __builtin_amdgcn_mfma_f32_16x16x32_bf16(a, bn_, aNI[rt], 0, 0, 0);
        }
    }
    const unsigned short* cR = pWhh + ((size_t)(0*8 + wv)*4)*512 + l*8;
    const unsigned short* cZ = pWhh + ((size_t)(1*8 + wv)*4)*512 + l*8;
    const unsigned short* cN = pWhh + ((size_t)(2*8 + wv)*4)*512 + l*8;
    for (int kt = 0; kt < 4; ++kt){
        bf16x8 br_ = ld8(cR + kt*512);
        bf16x8 bz_ = ld8(cZ + kt*512);
        bf16x8 bn_ = ld8(cN + kt*512);
        #pragma unroll
        for (int rt = 0; rt < 4; ++rt){
            int rowA = rt*16 + lr;
            bf16x8 a = ld8(&sGm[rowA*128 + (((kt*4 + lg) ^ (rowA&7))*8)]);
            aR[rt]  = __builtin_amdgcn_mfma_f32_16x16x32_bf16(a, br_, aR[rt], 0, 0, 0);
            aZ[rt]  = __builtin_amdgcn_mfma_f32_16x16x32_bf16(a, bz_, aZ[rt], 0, 0, 0);
            aNH[rt] = __builtin_amdgcn_mfma_f32_16x16x32_bf16(a, bn_, aNH[rt], 0, 0, 0);
        }
    }

    float b_r = bih[col] + bhh[col];
    float b_z = bih[DD+col] + bhh[DD+col];
    float b_ni = bih[2*DD+col];
    float b_nh = bhh[2*DD+col];
    #pragma unroll
    for (int rt = 0; rt < 4; ++rt){
        #pragma unroll
        for (int r4 = 0; r4 < 4; ++r4){
            int nl = rt*16 + lg*4 + r4;
            int n = n0 + nl;
            if (n < NN){
                float rg = sigmoidf_(aR[rt][r4] + b_r);
                float zg = sigmoidf_(aZ[rt][r4] + b_z);
                float ng = tanhf(aNI[rt][r4] + b_ni + rg*(aNH[rt][r4] + b_nh));
                float sg = bf2f(sGm[nl*128 + (((col>>3) ^ (nl&7))*8) + (col&7)]);
                float h = bf2f(sX[nl*256 + (((col>>3) ^ (nl&7))*8) + (col&7)]);
                outNode[(size_t)n*DD + col] = h + (1.f-zg)*ng + zg*sg;
            }
        }
    }
}

// ---------------- vector update: agg_v inline, VN-MLP, residual ----------------
__global__ __launch_bounds__(256) void k_vec(
    const float* __restrict__ vA, const float* __restrict__ vp,
    const float* __restrict__ hpp, const float* __restrict__ acc,
    const float* __restrict__ Wr2, const float* __restrict__ br2,
    const float* __restrict__ Wr3, const float* __restrict__ br3,
    const float* __restrict__ W1, const float* __restrict__ U1,
    const float* __restrict__ W2, float* __restrict__ outV)
{
    __shared__ float sW1[32*32], sU1[32*32], sW2[16*32];
    __shared__ float sWr2[RR*FF], sWr3[RR*FF];
    __shared__ float sVin[8][32][3];
    __shared__ float sVh[8][32][3];
    __shared__ float sAcc[8][64];
    __shared__ float sVA[8][48];
    int tid = threadIdx.x;
    for (int i = tid; i < 1024; i += 256){ sW1[i]=W1[i]; sU1[i]=U1[i]; }
    for (int i = tid; i < 512; i += 256) sW2[i]=W2[i];
    for (int i = tid; i < RR*FF; i += 256){ sWr2[i]=Wr2[i]; sWr3[i]=Wr3[i]; }
    int n0 = blockIdx.x*8;
    for (int i = tid; i < 8*64; i += 256) sAcc[i/64][i%64] = acc[(size_t)n0*64 + i];
    for (int i = tid; i < 8*48; i += 256) sVA[i/48][i%48] = vA[(size_t)n0*48 + i];
    __syncthreads();
    int t = tid >> 5, g = tid & 31;
    int n = n0 + t;
    if (g < 16){
        int f = g;
        float cnt = sAcc[t][0];
        float den = fmaxf(cnt, 1.f);
        float s1 = cnt*br2[f];
        #pragma unroll
        for (int r = 0; r < RR; ++r) s1 += sAcc[t][1+r]*sWr2[r*FF+f];
        float hpv = hpp[(size_t)n*FF+f];
        float b3 = br3[f];
        #pragma unroll
        for (int c = 0; c < 3; ++c){
            float s2 = b3*sAcc[t][16+c];
            #pragma unroll
            for (int r = 0; r < RR; ++r) s2 += sAcc[t][19+r*3+c]*sWr3[r*FF+f];
            float aggv = (vp[(size_t)n*48 + f*3 + c]*s1 + hpv*s2)/den;
            sVin[t][FF+f][c] = aggv;
            sVin[t][f][c] = sVA[t][f*3+c];
        }
    }
    __syncthreads();
    {
        float q0=0,q1=0,q2=0,k0=0,k1=0,k2=0;
        #pragma unroll
        for (int ff = 0; ff < 32; ++ff){
            int f = (ff + g) & 31;
            float w = sW1[g*32+f], u = sU1[g*32+f];
            float v0=sVin[t][f][0], v1=sVin[t][f][1], v2=sVin[t][f][2];
            q0+=w*v0;q1+=w*v1;q2+=w*v2;
            k0+=u*v0;k1+=u*v1;k2+=u*v2;
        }
        float dot=q0*k0+q1*k1+q2*k2;
        float ksq=k0*k0+k1*k1+k2*k2+EPSV;
        float s = dot>=0.f?0.f:dot/ksq;
        sVh[t][g][0]=q0-s*k0; sVh[t][g][1]=q1-s*k1; sVh[t][g][2]=q2-s*k2;
    }
    __syncthreads();
    if (g < 16){
        float o0=sVA[t][g*3+0], o1=sVA[t][g*3+1], o2=sVA[t][g*3+2];
        #pragma unroll
        for (int ff = 0; ff < 32; ++ff){
            int f = (ff + g) & 31;
            float w = sW2[g*32+f];
            o0 += w*sVh[t][f][0];
            o1 += w*sVh[t][f][1];
            o2 += w*sVh[t][f][2];
        }
        outV[(size_t)n*48 + g*3 + 0] = o0;
        outV[(size_t)n*48 + g*3 + 1] = o1;
        outV[(size_t)n*48 + g*3 + 2] = o2;
    }
}

extern "C" void kernel_launch(void* const* d_in, const int* in_sizes, int n_in,
                              void* d_out, int out_size, void* d_ws, size_t ws_size,
                              hipStream_t stream)
{
    const float* hA   = (const float*)d_in[0];
    const float* vA   = (const float*)d_in[1];
    const float* xA   = (const float*)d_in[2];
    const float* hB   = (const float*)d_in[3];
    const float* mask = (const float*)d_in[4];
    const int*   src  = (const int*)d_in[5];
    const int*   dst  = (const int*)d_in[6];
    const float* rbfk = (const float*)d_in[7];
    const float* Wr1  = (const float*)d_in[8];
    const float* br1  = (const float*)d_in[9];
    const float* Wr2  = (const float*)d_in[10];
    const float* br2  = (const float*)d_in[11];
    const float* Wr3  = (const float*)d_in[12];
    const float* br3  = (const float*)d_in[13];
    const float* vn1W = (const float*)d_in[14];
    const float* vn1U = (const float*)d_in[15];
    const float* vn2W = (const float*)d_in[16];
    const float* vn2U = (const float*)d_in[17];
    const float* vn3W = (const float*)d_in[18];
    const float* vn3U = (const float*)d_in[19];
    const float* phi1W= (const float*)d_in[20];
    const float* phi1b= (const float*)d_in[21];
    const float* phi2W= (const float*)d_in[22];
    const float* phi2b= (const float*)d_in[23];
    const float* phi3W= (const float*)d_in[24];
    const float* phi3b= (const float*)d_in[25];
    const float* Wq   = (const float*)d_in[26];
    const float* Wk   = (const float*)d_in[27];
    const float* Wv   = (const float*)d_in[28];
    const float* bv   = (const float*)d_in[29];
    const float* Wih  = (const float*)d_in[30];
    const float* Whh  = (const float*)d_in[31];
    const float* bih  = (const float*)d_in[32];
    const float* bhh  = (const float*)d_in[33];
    const float* W1   = (const float*)d_in[34];
    const float* U1   = (const float*)d_in[35];
    const float* W2   = (const float*)d_in[36];

    float* ws = (float*)d_ws;
    unsigned short* hpB = (unsigned short*)ws; ws += (size_t)NN*DD/2;
    unsigned short* attnB = (unsigned short*)ws; ws += ((size_t)NBLK*64*128)/2;
    unsigned short* hAB = (unsigned short*)ws; ws += ((size_t)NBLK*64*128)/2;
    float* hpp    = ws;  ws += (size_t)NN*FF;
    float* vp     = ws;  ws += (size_t)NN*FF*3;
    float* acc    = ws;  ws += (size_t)NN*64;
    unsigned short* pWih = (unsigned short*)ws; ws += (size_t)3*8*8*512/2;
    unsigned short* pWhh = (unsigned short*)ws; ws += (size_t)3*8*4*512/2;
    unsigned short* pWq  = (unsigned short*)ws; ws += (size_t)8*4*512/2;
    unsigned short* pKK  = (unsigned short*)ws; ws += (size_t)16*4*512/2;
    unsigned short* pVV  = (unsigned short*)ws; ws += (size_t)8*8*512/2;
    unsigned short* pPhi1= (unsigned short*)ws; ws += (size_t)8*5*512/2;
    unsigned short* pPhi2= (unsigned short*)ws; ws += (size_t)5*512/2;
    unsigned short* pPhi3= (unsigned short*)ws; ws += (size_t)4*512/2;
    unsigned short* pWr1 = (unsigned short*)ws; ws += (size_t)8*512/2;
    int* deg    = (int*)ws;  ws += NN;
    int* excl   = (int*)ws;  ws += NN;
    int* bsum   = (int*)ws;  ws += 256;
    int* startN = (int*)ws;  ws += NN+1;
    int* cursor = (int*)ws;  ws += NN;
    int* esrc   = (int*)ws;  ws += EE;

    float* outV = (float*)d_out;
    float* outH = (float*)d_out + (size_t)NN*FF*3;

    const int NB_SCAN = (NN + 255)/256;   // 196

    k_prep<<<512, 256, 0, stream>>>(Wih, Whh, Wq, phi1W, phi2W, phi3W, Wr1, br1,
                                    hB, Wk, Wv, bv,
                                    pWih, pWhh, pWq, pPhi1, pPhi2, pPhi3, pWr1,
                                    pKK, pVV, deg);
    k_hist<<<(EE+255)/256, 256, 0, stream>>>(dst, deg);
    k_scan1<<<NB_SCAN, 256, 0, stream>>>(deg, excl, bsum);
    k_scan23<<<NB_SCAN, 256, 0, stream>>>(excl, bsum, NB_SCAN, startN, cursor);
    k_scatter<<<(EE+255)/256, 256, 0, stream>>>(src, dst, cursor, esrc);
    k_node<<<NBLK, 512, 0, stream>>>(hA, vA, vn1W, vn1U, vn2W, vn2U, vn3W, vn3U,
                                     pPhi1, phi1b, pPhi2, phi2b, pPhi3, phi3b,
                                     hpB, hpp, vp, hAB);
    k_ga_attn<<<NGA + NBLK, 512, 0, stream>>>(startN, esrc, xA, rbfk, acc,
                                              hAB, pWq, pKK, pVV, mask, attnB);
    k_gru_mfma<<<NBLK, 512, 0, stream>>>(hAB, attnB, hpB, acc, pWr1,
                                         pWih, pWhh, bih, bhh, outH);
    k_vec<<<NN/8, 256, 0, stream>>>(vA, vp, hpp, acc, Wr2, br2, Wr3, br3, W1, U1, W2, outV);
}

// Round 24
// 318.750 us; speedup vs baseline: 1.0448x; 1.0448x over previous
//
#include <hip/hip_runtime.h>
#include <math.h>

#define NN 50000
#define NBB 256
#define DD 128
#define FF 16
#define EE 800000
#define RR 15
#define EPSV 1e-7f
#define CSPACE (5.0f/14.0f)
#define NBLK 782   // ceil(NN/64)
#define NGA 391    // gather blocks @512thr (NN*4/512)

__device__ __forceinline__ float lrelu(float x){ return x >= 0.f ? x : 0.01f*x; }
__device__ __forceinline__ float sigmoidf_(float x){ return 1.f/(1.f+expf(-x)); }

typedef __bf16 bf16x8 __attribute__((ext_vector_type(8)));
typedef float f32x4 __attribute__((ext_vector_type(4)));

__device__ __forceinline__ unsigned short f2bf(float x){
    union { float f; unsigned int u; } a; a.f = x;
    unsigned int r = (a.u + 0x7fffu + ((a.u >> 16) & 1u)) >> 16;
    return (unsigned short)r;
}
__device__ __forceinline__ unsigned int pack2(float a, float b){
    return (unsigned int)f2bf(a) | ((unsigned int)f2bf(b) << 16);
}
__device__ __forceinline__ float bf2f(unsigned short v){
    union { unsigned int u; float f; } a; a.u = ((unsigned int)v) << 16; return a.f;
}
__device__ __forceinline__ bf16x8 ld8(const unsigned short* p){
    union { uint4 u; bf16x8 b; } x; x.u = *(const uint4*)p; return x.b;
}

// ---------------- pack weights + zero deg + kv projection (blocks >= 384) ----------------
__global__ __launch_bounds__(256) void k_prep(
    const float* __restrict__ Wih, const float* __restrict__ Whh,
    const float* __restrict__ Wq,
    const float* __restrict__ phi1W, const float* __restrict__ phi2W,
    const float* __restrict__ phi3W,
    const float* __restrict__ Wr1, const float* __restrict__ br1,
    const float* __restrict__ hB, const float* __restrict__ Wk,
    const float* __restrict__ Wv, const float* __restrict__ bv,
    unsigned short* __restrict__ pWih, unsigned short* __restrict__ pWhh,
    unsigned short* __restrict__ pWq,
    unsigned short* __restrict__ pPhi1, unsigned short* __restrict__ pPhi2,
    unsigned short* __restrict__ pPhi3, unsigned short* __restrict__ pWr1,
    unsigned short* __restrict__ pKK, unsigned short* __restrict__ pVV,
    int* __restrict__ deg)
{
    if (blockIdx.x >= 384){
        __shared__ float sB[2][DD];
        int sub = threadIdx.x >> 7, j = threadIdx.x & 127;
        int b = (blockIdx.x - 384)*2 + sub;
        sB[sub][j] = hB[(size_t)b*DD + j];
        __syncthreads();
        float ak = 0.f, av = bv[j];
        for (int i = 0; i < DD; ++i){
            float h = sB[sub][i];
            ak += h*Wk[i*DD+j];
            av += h*Wv[i*DD+j];
        }
        {
            int c = b>>4, lr = b&15, kt = j>>5, lg = (j>>3)&3, e = j&7;
            pKK[((c*4+kt)*64 + lg*16 + lr)*8 + e] = f2bf(lrelu(ak));
        }
        {
            int kt = b>>5, lg = (b>>3)&3, e = b&7, c = j>>4, lr = j&15;
            pVV[((c*8+kt)*64 + lg*16 + lr)*8 + e] = f2bf(av);
        }
        return;
    }
    int i = blockIdx.x*256 + threadIdx.x;
    if (i < NN) deg[i] = 0;
    if (i < 3*8*8*64*8){
        int e = i&7, l=(i>>3)&63, kt=(i>>9)&7, c=(i>>12)&7, q=i>>15;
        int row = q*128 + c*16 + (l&15);
        int k = kt*32 + (l>>4)*8 + e;
        pWih[i] = f2bf(Wih[row*256 + k]);
    }
    if (i < 3*8*4*64*8){
        int e = i&7, l=(i>>3)&63, kt=(i>>9)&3, c=(i>>11)&7, q=i>>14;
        int row = q*128 + c*16 + (l&15);
        int k = kt*32 + (l>>4)*8 + e;
        pWhh[i] = f2bf(Whh[row*128 + k]);
    }
    if (i < 8*4*64*8){
        int e = i&7, l=(i>>3)&63, kt=(i>>9)&3, c=(i>>11)&7;
        pWq[i] = f2bf(Wq[(kt*32 + (l>>4)*8 + e)*DD + c*16 + (l&15)]);
    }
    if (i < 8*5*64*8){
        int e = i&7, l=(i>>3)&63;
        int t = i>>9;
        int kt = t%5, c = t/5;
        int k = kt*32 + (l>>4)*8 + e;
        int col = c*16 + (l&15);
        pPhi1[i] = f2bf(k < 144 ? phi1W[k*DD + col] : 0.f);
    }
    if (i < 5*64*8){
        int e = i&7, l=(i>>3)&63, kt = i>>9;
        int k = kt*32 + (l>>4)*8 + e;
        int col = l&15;
        pPhi2[i] = f2bf(k < 144 ? phi2W[k*FF + col] : 0.f);
    }
    if (i < 4*64*8){
        int e = i&7, l=(i>>3)&63, kt = i>>9;
        int k = kt*32 + (l>>4)*8 + e;
        int col = l&15;
        pPhi3[i] = f2bf(phi3W[k*FF + col]);
    }
    if (i < 8*64*8){
        int e = i&7, l=(i>>3)&63, c = i>>9;
        int col = c*16 + (l&15);
        int k = (l>>4)*8 + e;
        float v = 0.f;
        if (k == 0) v = br1[col];
        else if (k < 16) v = Wr1[(k-1)*DD + col];
        pWr1[i] = f2bf(v);
    }
}

// ---------------- fused per-node features; publishes hA bf16 swizzled image ----------------
__global__ __launch_bounds__(512) void k_node(
    const float* __restrict__ hA, const float* __restrict__ vA,
    const float* __restrict__ vn1W, const float* __restrict__ vn1U,
    const float* __restrict__ vn2W, const float* __restrict__ vn2U,
    const float* __restrict__ vn3W, const float* __restrict__ vn3U,
    const unsigned short* __restrict__ pPhi1, const float* __restrict__ phi1b,
    const unsigned short* __restrict__ pPhi2, const float* __restrict__ phi2b,
    const unsigned short* __restrict__ pPhi3, const float* __restrict__ phi3b,
    unsigned short* __restrict__ hpB, float* __restrict__ hppO, float* __restrict__ vpO,
    unsigned short* __restrict__ hAB)
{
    __shared__ unsigned short sH[64*128];
    __shared__ unsigned short sE[64*64];
    __shared__ float sVA[64*48];
    __shared__ float sO3[64*16*3];
    __shared__ float sW[6*256];
    int tid = threadIdx.x;
    int n0 = blockIdx.x*64;

    #pragma unroll
    for (int it = 0; it < 2; ++it){
        int c = tid + it*512;
        int row = c >> 4, cb = c & 15;
        int gn = n0 + row; if (gn > NN-1) gn = NN-1;
        const float* p = hA + (size_t)gn*DD + cb*8;
        float4 f0 = *(const float4*)p;
        float4 f1 = *(const float4*)(p+4);
        uint4 u;
        u.x = pack2(f0.x,f0.y); u.y = pack2(f0.z,f0.w);
        u.z = pack2(f1.x,f1.y); u.w = pack2(f1.z,f1.w);
        *(uint4*)&sH[row*128 + ((cb ^ (row&7))*8)] = u;
    }
    #pragma unroll
    for (int it = 0; it < 6; ++it){
        int i = tid + it*512;
        int row = i/48, cc = i%48;
        int gn = n0 + row; if (gn > NN-1) gn = NN-1;
        sVA[i] = vA[(size_t)gn*48 + cc];
    }
    #pragma unroll
    for (int it = 0; it < 3; ++it){
        int i = tid + it*512;
        float v;
        if      (i <  256) v = vn1W[i];
        else if (i <  512) v = vn1U[i-256];
        else if (i <  768) v = vn2W[i-512];
        else if (i < 1024) v = vn2U[i-768];
        else if (i < 1280) v = vn3W[i-1024];
        else               v = vn3U[i-1280];
        sW[i] = v;
    }
    {
        uint2* z = (uint2*)sE;
        z[tid] = make_uint2(0u,0u);
        z[tid+512] = make_uint2(0u,0u);
    }
    __syncthreads();

    #pragma unroll
    for (int it = 0; it < 2; ++it){
        int i = tid + it*512;
        ((uint4*)hAB)[(size_t)blockIdx.x*1024 + i] = ((const uint4*)sH)[i];
    }

    #pragma unroll
    for (int it = 0; it < 2; ++it){
        int item = tid + it*512;
        int nl = item >> 4, g = item & 15;
        const float* v = &sVA[nl*48];
        float q0[3]={0,0,0}, q1[3]={0,0,0}, q2[3]={0,0,0};
        float c0[3]={0,0,0}, c1[3]={0,0,0}, c2[3]={0,0,0};
        #pragma unroll
        for (int ff = 0; ff < FF; ++ff){
            int fi = (ff + g) & 15;
            float v0 = v[fi*3], v1 = v[fi*3+1], v2 = v[fi*3+2];
            #pragma unroll
            for (int m = 0; m < 3; ++m){
                float w = sW[m*512 + g*16 + fi];
                float u = sW[m*512 + 256 + g*16 + fi];
                q0[m] += w*v0; q1[m] += w*v1; q2[m] += w*v2;
                c0[m] += u*v0; c1[m] += u*v1; c2[m] += u*v2;
            }
        }
        #pragma unroll
        for (int m = 0; m < 3; ++m){
            float dot = q0[m]*c0[m] + q1[m]*c1[m] + q2[m]*c2[m];
            float ksq = c0[m]*c0[m] + c1[m]*c1[m] + c2[m]*c2[m] + EPSV;
            float s = dot >= 0.f ? 0.f : dot/ksq;
            float o0 = q0[m]-s*c0[m], o1 = q1[m]-s*c1[m], o2 = q2[m]-s*c2[m];
            if (m < 2){
                float nr = sqrtf(o0*o0+o1*o1+o2*o2) + EPSV;
                int col = (m==0) ? g : (32+g);
                int cb = col>>3;
                sE[nl*64 + ((cb ^ (nl&7))*8) + (col&7)] = f2bf(nr);
            } else {
                float* o = &sO3[(nl*16+g)*3];
                o[0]=o0; o[1]=o1; o[2]=o2;
            }
        }
    }
    __syncthreads();

    int wv = tid>>6, l = tid&63, lr = l&15, lg = l>>4;

    f32x4 a1[4];
    #pragma unroll
    for (int rt = 0; rt < 4; ++rt) a1[rt] = (f32x4){0.f,0.f,0.f,0.f};
    for (int kt = 0; kt < 4; ++kt){
        bf16x8 b = ld8(pPhi1 + ((size_t)(wv*5+kt)*64 + l)*8);
        #pragma unroll
        for (int rt = 0; rt < 4; ++rt){
            int row = rt*16 + lr;
            bf16x8 a = ld8(&sH[row*128 + (((kt*4+lg) ^ (row&7))*8)]);
            a1[rt] = __builtin_amdgcn_mfma_f32_16x16x32_bf16(a, b, a1[rt], 0, 0, 0);
        }
    }
    {
        bf16x8 b = ld8(pPhi1 + ((size_t)(wv*5+4)*64 + l)*8);
        #pragma unroll
        for (int rt = 0; rt < 4; ++rt){
            int row = rt*16 + lr;
            bf16x8 a = ld8(&sE[row*64 + ((lg ^ (row&7))*8)]);
            a1[rt] = __builtin_amdgcn_mfma_f32_16x16x32_bf16(a, b, a1[rt], 0, 0, 0);
        }
    }
    f32x4 a23 = (f32x4){0.f,0.f,0.f,0.f};
    if (wv < 4){
        int row = wv*16 + lr;
        for (int kt = 0; kt < 4; ++kt){
            bf16x8 b = ld8(pPhi3 + ((size_t)kt*64 + l)*8);
            bf16x8 a = ld8(&sH[row*128 + (((kt*4+lg) ^ (row&7))*8)]);
            a23 = __builtin_amdgcn_mfma_f32_16x16x32_bf16(a, b, a23, 0, 0, 0);
        }
    } else {
        int row = (wv-4)*16 + lr;
        for (int kt = 0; kt < 4; ++kt){
            bf16x8 b = ld8(pPhi2 + ((size_t)kt*64 + l)*8);
            bf16x8 a = ld8(&sH[row*128 + (((kt*4+lg) ^ (row&7))*8)]);
            a23 = __builtin_amdgcn_mfma_f32_16x16x32_bf16(a, b, a23, 0, 0, 0);
        }
        {
            bf16x8 b = ld8(pPhi2 + ((size_t)4*64 + l)*8);
            bf16x8 a = ld8(&sE[row*64 + (((4+lg) ^ (row&7))*8)]);
            a23 = __builtin_amdgcn_mfma_f32_16x16x32_bf16(a, b, a23, 0, 0, 0);
        }
    }

    {
        int col = wv*16 + lr;
        float b1 = phi1b[col];
        #pragma unroll
        for (int rt = 0; rt < 4; ++rt){
            #pragma unroll
            for (int r4 = 0; r4 < 4; ++r4){
                int n = n0 + rt*16 + lg*4 + r4;
                if (n < NN) hpB[(size_t)n*DD + col] = f2bf(lrelu(a1[rt][r4] + b1));
            }
        }
    }
    if (wv < 4){
        float b3 = phi3b[lr];
        #pragma unroll
        for (int r4 = 0; r4 < 4; ++r4){
            int nl = wv*16 + lg*4 + r4;
            int n = n0 + nl;
            float gate = lrelu(a23[r4] + b3);
            if (n < NN){
                const float* o = &sO3[(nl*16+lr)*3];
                float* vo = vpO + (size_t)n*48 + lr*3;
                vo[0] = o[0]*gate; vo[1] = o[1]*gate; vo[2] = o[2]*gate;
            }
        }
    } else {
        float b2 = phi2b[lr];
        #pragma unroll
        for (int r4 = 0; r4 < 4; ++r4){
            int nl = (wv-4)*16 + lg*4 + r4;
            int n = n0 + nl;
            if (n < NN) hppO[(size_t)n*FF + lr] = lrelu(a23[r4] + b2);
        }
    }
}

// ---------------- edge phase ----------------
__global__ __launch_bounds__(256) void k_hist(const int* __restrict__ dst, int* __restrict__ deg){
    int e = blockIdx.x*256 + threadIdx.x;
    if (e < EE) atomicAdd(&deg[dst[e]], 1);
}

__global__ __launch_bounds__(256) void k_scan1(const int* __restrict__ deg,
                                               int* __restrict__ excl, int* __restrict__ bsum){
    __shared__ int s[256];
    int tid = threadIdx.x;
    int i = blockIdx.x*256 + tid;
    int v = (i < NN) ? deg[i] : 0;
    s[tid] = v;
    __syncthreads();
    for (int o = 1; o < 256; o <<= 1){
        int t = 0;
        if (tid >= o) t = s[tid-o];
        __syncthreads();
        if (tid >= o) s[tid] += t;
        __syncthreads();
    }
    if (i < NN) excl[i] = s[tid] - v;
    if (tid == 255) bsum[blockIdx.x] = s[255];
}

__global__ __launch_bounds__(256) void k_scan23(const int* __restrict__ excl,
                                                const int* __restrict__ bsum, int nb,
                                                int* __restrict__ start, int* __restrict__ cursor){
    __shared__ int s[256];
    int tid = threadIdx.x;
    int v = (tid < nb) ? bsum[tid] : 0;
    s[tid] = v;
    __syncthreads();
    for (int o = 1; o < 256; o <<= 1){
        int t = 0;
        if (tid >= o) t = s[tid-o];
        __syncthreads();
        if (tid >= o) s[tid] += t;
        __syncthreads();
    }
    int boff = (blockIdx.x == 0) ? 0 : s[blockIdx.x - 1];
    int i = blockIdx.x*256 + tid;
    if (i < NN){
        int st = excl[i] + boff;
        start[i] = st;
        cursor[i] = st;
    }
    if (i == 0) start[NN] = EE;
}

__global__ __launch_bounds__(256) void k_scatter(const int* __restrict__ src,
                                                 const int* __restrict__ dst,
                                                 int* __restrict__ cursor, int* __restrict__ esrc){
    int e = blockIdx.x*256 + threadIdx.x;
    if (e >= EE) return;
    int pos = atomicAdd(&cursor[dst[e]], 1);
    esrc[pos] = src[e];
}

// ---------------- MERGED: gather (blocks < NGA, single-pass) + attention ----------------
__global__ __launch_bounds__(512) void k_ga_attn(
    const int* __restrict__ start, const int* __restrict__ esrc,
    const float* __restrict__ xA, const float* __restrict__ rbf_k,
    float* __restrict__ acc,
    const unsigned short* __restrict__ hAB, const unsigned short* __restrict__ pWq,
    const unsigned short* __restrict__ pKK, const unsigned short* __restrict__ pVV,
    const float* __restrict__ mask, unsigned short* __restrict__ attnB)
{
    __shared__ __align__(16) unsigned char smem[33792];
    int tid = threadIdx.x;
    if (blockIdx.x < NGA){
        int gt = blockIdx.x*512 + tid;
        int n = gt >> 2, sub = gt & 3;
        if (n >= NN) return;
        float kc = rbf_k[0];
        float xd0 = xA[n*3+0], xd1 = xA[n*3+1], xd2 = xA[n*3+2];
        float a[64];
        #pragma unroll
        for (int i = 0; i < 64; ++i) a[i] = 0.f;
        int b0 = start[n], b1 = start[n+1];
        for (int i = b0 + sub; i < b1; i += 4){
            int s = esrc[i];
            float r0 = xA[s*3+0]-xd0, r1 = xA[s*3+1]-xd1, r2 = xA[s*3+2]-xd2;
            float rn = sqrtf(r0*r0+r1*r1+r2*r2);
            a[0] += 1.f;
            a[16] += r0; a[17] += r1; a[18] += r2;
            #pragma unroll
            for (int q = 0; q < RR; ++q){
                float df = rn - (float)q*CSPACE;
                float rb = expf(-df*df*kc);
                a[1+q] += rb;
                a[19+q*3+0] += rb*r0;
                a[19+q*3+1] += rb*r1;
                a[19+q*3+2] += rb*r2;
            }
        }
        #pragma unroll
        for (int i = 0; i < 64; ++i){
            a[i] += __shfl_xor(a[i], 1);
            a[i] += __shfl_xor(a[i], 2);
        }
        float4* o = (float4*)(acc + (size_t)n*64);
        #pragma unroll
        for (int i = 0; i < 4; ++i){
            int idx = sub*4 + i;
            o[idx] = make_float4(a[4*idx], a[4*idx+1], a[4*idx+2], a[4*idx+3]);
        }
        return;
    }
    int ab = blockIdx.x - NGA;
    unsigned short* sU = (unsigned short*)smem;
    float* sMx = (float*)(smem + 32768);
    float* sSm = (float*)(smem + 33280);
    unsigned short* sX = sU;
    unsigned short* sQ = sU + 64*128;
    unsigned short* sP = sU;
    unsigned short* sImg = sU;
    int n0 = ab*64;

    #pragma unroll
    for (int it = 0; it < 2; ++it){
        int i = tid + it*512;
        ((uint4*)sX)[i] = ((const uint4*)hAB)[(size_t)ab*1024 + i];
    }
    __syncthreads();

    int wv = tid>>6, l = tid&63, lr = l&15, lg = l>>4;
    int rw = wv>>1, chh = wv&1;
    int rowA = rw*16 + lr;

    {
        f32x4 q[4];
        #pragma unroll
        for (int c = 0; c < 4; ++c) q[c] = (f32x4){0.f,0.f,0.f,0.f};
        for (int kt = 0; kt < 4; ++kt){
            bf16x8 a = ld8(&sX[rowA*128 + (((kt*4+lg) ^ (rowA&7))*8)]);
            #pragma unroll
            for (int c = 0; c < 4; ++c){
                bf16x8 b = ld8(pWq + (size_t)(((chh*4+c)*4 + kt)*512) + l*8);
                q[c] = __builtin_amdgcn_mfma_f32_16x16x32_bf16(a, b, q[c], 0, 0, 0);
            }
        }
        __syncthreads();
        #pragma unroll
        for (int c = 0; c < 4; ++c)
        #pragma unroll
        for (int r4 = 0; r4 < 4; ++r4){
            int row = rw*16 + lg*4 + r4;
            int col = chh*64 + c*16 + lr;
            int cb = col>>3;
            sQ[row*128 + ((cb ^ (row&7))*8) + (col&7)] = f2bf(lrelu(q[c][r4]));
        }
    }
    __syncthreads();

    f32x4 S[8];
    #pragma unroll
    for (int cl = 0; cl < 8; ++cl) S[cl] = (f32x4){0.f,0.f,0.f,0.f};
    for (int kt = 0; kt < 4; ++kt){
        bf16x8 a = ld8(&sQ[rowA*128 + (((kt*4+lg) ^ (rowA&7))*8)]);
        #pragma unroll
        for (int cl = 0; cl < 8; ++cl){
            bf16x8 b = ld8(pKK + (size_t)(((chh*8+cl)*4 + kt)*512) + l*8);
            S[cl] = __builtin_amdgcn_mfma_f32_16x16x32_bf16(a, b, S[cl], 0, 0, 0);
        }
    }
    float den[4];
    #pragma unroll
    for (int r4 = 0; r4 < 4; ++r4){
        int row = rw*16 + lg*4 + r4;
        int gn = n0 + row; if (gn > NN-1) gn = NN-1;
        float mx = -1e30f;
        #pragma unroll
        for (int cl = 0; cl < 8; ++cl){
            int col = chh*128 + cl*16 + lr;
            float m = mask[(size_t)gn*NBB + col];
            float s = m*S[cl][r4] - 1000.f*(1.f-m);
            S[cl][r4] = s;
            mx = fmaxf(mx, s);
        }
        mx = fmaxf(mx, __shfl_xor(mx, 1));
        mx = fmaxf(mx, __shfl_xor(mx, 2));
        mx = fmaxf(mx, __shfl_xor(mx, 4));
        mx = fmaxf(mx, __shfl_xor(mx, 8));
        if (lr == 0) sMx[row*2+chh] = mx;
    }
    __syncthreads();
    #pragma unroll
    for (int r4 = 0; r4 < 4; ++r4){
        int row = rw*16 + lg*4 + r4;
        float m = fmaxf(sMx[row*2+0], sMx[row*2+1]);
        float sm = 0.f;
        #pragma unroll
        for (int cl = 0; cl < 8; ++cl){
            float p = expf(S[cl][r4] - m);
            S[cl][r4] = p;
            sm += p;
        }
        sm += __shfl_xor(sm, 1);
        sm += __shfl_xor(sm, 2);
        sm += __shfl_xor(sm, 4);
        sm += __shfl_xor(sm, 8);
        if (lr == 0) sSm[row*2+chh] = sm;
    }
    __syncthreads();
    #pragma unroll
    for (int r4 = 0; r4 < 4; ++r4){
        int row = rw*16 + lg*4 + r4;
        den[r4] = sSm[row*2+0] + sSm[row*2+1];
    }
    #pragma unroll
    for (int cl = 0; cl < 8; ++cl)
    #pragma unroll
    for (int r4 = 0; r4 < 4; ++r4){
        int row = rw*16 + lg*4 + r4;
        int col = chh*128 + cl*16 + lr;
        int cb = col>>3;
        sP[row*256 + ((cb ^ (row&7))*8) + (col&7)] = f2bf(S[cl][r4]);
    }
    __syncthreads();

    f32x4 O[4];
    #pragma unroll
    for (int c = 0; c < 4; ++c) O[c] = (f32x4){0.f,0.f,0.f,0.f};
    for (int kt = 0; kt < 8; ++kt){
        bf16x8 a = ld8(&sP[rowA*256 + (((kt*4+lg) ^ (rowA&7))*8)]);
        #pragma unroll
        for (int c = 0; c < 4; ++c){
            bf16x8 b = ld8(pVV + (size_t)(((chh*4+c)*8 + kt)*512) + l*8);
            O[c] = __builtin_amdgcn_mfma_f32_16x16x32_bf16(a, b, O[c], 0, 0, 0);
        }
    }
    __syncthreads();
    #pragma unroll
    for (int c = 0; c < 4; ++c)
    #pragma unroll
    for (int r4 = 0; r4 < 4; ++r4){
        int row = rw*16 + lg*4 + r4;
        int col = chh*64 + c*16 + lr;
        sImg[row*128 + (((col>>3) ^ (row&7))*8) + (col&7)] = f2bf(O[c][r4] / den[r4]);
    }
    __syncthreads();
    #pragma unroll
    for (int it = 0; it < 2; ++it){
        int i = tid + it*512;
        ((uint4*)attnB)[(size_t)ab*1024 + i] = ((const uint4*)sImg)[i];
    }
}

// ---------------- GRU via bf16 MFMA; both input halves = verbatim image copies ----------------
__global__ __launch_bounds__(512) void k_gru_mfma(
    const unsigned short* __restrict__ hAB, const unsigned short* __restrict__ attnB,
    const unsigned short* __restrict__ hpB, const float* __restrict__ acc,
    const unsigned short* __restrict__ pWr1,
    const unsigned short* __restrict__ pWih, const unsigned short* __restrict__ pWhh,
    const float* __restrict__ bih, const float* __restrict__ bhh,
    float* __restrict__ outNode)
{
    __shared__ unsigned short sX[64*256];   // 32KB
    __shared__ unsigned short sGm[64*128];  // 16KB; head doubles as sM
    __shared__ float sCnt[64];
    unsigned short* sM = sGm;
    int tid = threadIdx.x;
    int n0 = blockIdx.x*64;

    #pragma unroll
    for (int it = 0; it < 2; ++it){
        int i = tid + it*512;
        uint4 v = ((const uint4*)hAB)[(size_t)blockIdx.x*1024 + i];
        int row = i >> 4, p = i & 15;
        *(uint4*)&sX[row*256 + p*8] = v;
    }
    #pragma unroll
    for (int it = 0; it < 2; ++it){
        int i = tid + it*512;
        uint4 v = ((const uint4*)attnB)[(size_t)blockIdx.x*1024 + i];
        int row = i >> 4, p = i & 15;
        *(uint4*)&sX[row*256 + 128 + p*8] = v;
    }
    #pragma unroll
    for (int it = 0; it < 4; ++it){
        int i = tid + it*512;
        int row = i >> 5, k = i & 31;
        int gn = n0 + row; if (gn > NN-1) gn = NN-1;
        float v = (k < 16) ? acc[(size_t)gn*64 + k] : 0.f;
        sM[row*40 + k] = f2bf(v);
        if (k == 0) sCnt[row] = v;
    }
    __syncthreads();

    int wv = tid >> 6, l = tid & 63;
    int lr = l & 15, lg = l >> 4;
    int col = wv*16 + lr;

    {
        f32x4 sv[4];
        #pragma unroll
        for (int rt = 0; rt < 4; ++rt) sv[rt] = (f32x4){0.f,0.f,0.f,0.f};
        bf16x8 b = ld8(pWr1 + (size_t)wv*512 + l*8);
        #pragma unroll
        for (int rt = 0; rt < 4; ++rt){
            int row = rt*16 + lr;
            bf16x8 a = ld8(&sM[row*40 + lg*8]);
            sv[rt] = __builtin_amdgcn_mfma_f32_16x16x32_bf16(a, b, sv[rt], 0, 0, 0);
        }
        __syncthreads();
        #pragma unroll
        for (int rt = 0; rt < 4; ++rt){
            #pragma unroll
            for (int r4 = 0; r4 < 4; ++r4){
                int row = rt*16 + lg*4 + r4;
                int gn = n0 + row; if (gn > NN-1) gn = NN-1;
                float cnt = sCnt[row];
                float den = fmaxf(cnt, 1.f);
                float g = bf2f(hpB[(size_t)gn*DD + col]) * sv[rt][r4] / den;
                sGm[row*128 + (((col>>3) ^ (row&7))*8) + (col&7)] = f2bf(g);
            }
        }
    }
    __syncthreads();

    f32x4 aR[4], aZ[4], aNI[4], aNH[4];
    #pragma unroll
    for (int rt = 0; rt < 4; ++rt){
        aR[rt] = (f32x4){0.f,0.f,0.f,0.f};
        aZ[rt] = (f32x4){0.f,0.f,0.f,0.f};
        aNI[rt] = (f32x4){0.f,0.f,0.f,0.f};
        aNH[rt] = (f32x4){0.f,0.f,0.f,0.f};
    }
    const unsigned short* bR = pWih + ((size_t)(0*8 + wv)*8)*512 + l*8;
    const unsigned short* bZ = pWih + ((size_t)(1*8 + wv)*8)*512 + l*8;
    const unsigned short* bN = pWih + ((size_t)(2*8 + wv)*8)*512 + l*8;
    for (int kt = 0; kt < 8; ++kt){
        bf16x8 br_ = ld8(bR + kt*512);
        bf16x8 bz_ = ld8(bZ + kt*512);
        bf16x8 bn_ = ld8(bN + kt*512);
        #pragma unroll
        for (int rt = 0; rt < 4; ++rt){
            int rowA = rt*16 + lr;
            bf16x8 a = ld8(&sX[rowA*256 + (((kt*4 + lg) ^ (rowA&7))*8)]);
            aR[rt]  = __builtin_amdgcn_mfma_f32_16x16x32_bf16(a, br_, aR[rt], 0, 0, 0);
            aZ[rt]  = __builtin_amdgcn_mfma_f32_16x16x32_bf16(a, bz_, aZ[rt], 0, 0, 0);
            aNI[rt] = __builtin_amdgcn_mfma_f32_16x16x32_bf16(a, bn_, aNI[rt], 0, 0, 0);
        }
    }
    const unsigned short* cR = pWhh + ((size_t)(0*8 + wv)*4)*512 + l*8;
    const unsigned short* cZ = pWhh + ((size_t)(1*8 + wv)*4)*512 + l*8;
    const unsigned short* cN = pWhh + ((size_t)(2*8 + wv)*4)*512 + l*8;
    for (int kt = 0; kt < 4; ++kt){
        bf16x8 br_ = ld8(cR + kt*512);
        bf16x8 bz_ = ld8(cZ + kt*512);
        bf16x8 bn_ = ld8(cN + kt*512);
        #pragma unroll
        for (int rt = 0; rt < 4; ++rt){
            int rowA = rt*16 + lr;
            bf16x8 a = ld8(&sGm[rowA*128 + (((kt*4 + lg) ^ (rowA&7))*8)]);
            aR[rt]  = __builtin_amdgcn_mfma_f32_16x16x32_bf16(a, br_, aR[rt], 0, 0, 0);
            aZ[rt]  = __builtin_amdgcn_mfma_f32_16x16x32_bf16(a, bz_, aZ[rt], 0, 0, 0);
            aNH[rt] = __builtin_amdgcn_mfma_f32_16x16x32_bf16(a, bn_, aNH[rt], 0, 0, 0);
        }
    }

    float b_r = bih[col] + bhh[col];
    float b_z = bih[DD+col] + bhh[DD+col];
    float b_ni = bih[2*DD+col];
    float b_nh = bhh[2*DD+col];
    #pragma unroll
    for (int rt = 0; rt < 4; ++rt){
        #pragma unroll
        for (int r4 = 0; r4 < 4; ++r4){
            int nl = rt*16 + lg*4 + r4;
            int n = n0 + nl;
            if (n < NN){
                float rg = sigmoidf_(aR[rt][r4] + b_r);
                float zg = sigmoidf_(aZ[rt][r4] + b_z);
                float ng = tanhf(aNI[rt][r4] + b_ni + rg*(aNH[rt][r4] + b_nh));
                float sg = bf2f(sGm[nl*128 + (((col>>3) ^ (nl&7))*8) + (col&7)]);
                float h = bf2f(sX[nl*256 + (((col>>3) ^ (nl&7))*8) + (col&7)]);
                outNode[(size_t)n*DD + col] = h + (1.f-zg)*ng + zg*sg;
            }
        }
    }
}

// ---------------- vector update: agg_v inline, VN-MLP, residual ----------------
__global__ __launch_bounds__(256) void k_vec(
    const float* __restrict__ vA, const float* __restrict__ vp,
    const float* __restrict__ hpp, const float* __restrict__ acc,
    const float* __restrict__ Wr2, const float* __restrict__ br2,
    const float* __restrict__ Wr3, const float* __restrict__ br3,
    const float* __restrict__ W1, const float* __restrict__ U1,
    const float* __restrict__ W2, float* __restrict__ outV)
{
    __shared__ float sW1[32*32], sU1[32*32], sW2[16*32];
    __shared__ float sWr2[RR*FF], sWr3[RR*FF];
    __shared__ float sVin[8][32][3];
    __shared__ float sVh[8][32][3];
    __shared__ float sAcc[8][64];
    __shared__ float sVA[8][48];
    int tid = threadIdx.x;
    for (int i = tid; i < 1024; i += 256){ sW1[i]=W1[i]; sU1[i]=U1[i]; }
    for (int i = tid; i < 512; i += 256) sW2[i]=W2[i];
    for (int i = tid; i < RR*FF; i += 256){ sWr2[i]=Wr2[i]; sWr3[i]=Wr3[i]; }
    int n0 = blockIdx.x*8;
    for (int i = tid; i < 8*64; i += 256) sAcc[i/64][i%64] = acc[(size_t)n0*64 + i];
    for (int i = tid; i < 8*48; i += 256) sVA[i/48][i%48] = vA[(size_t)n0*48 + i];
    __syncthreads();
    int t = tid >> 5, g = tid & 31;
    int n = n0 + t;
    if (g < 16){
        int f = g;
        float cnt = sAcc[t][0];
        float den = fmaxf(cnt, 1.f);
        float s1 = cnt*br2[f];
        #pragma unroll
        for (int r = 0; r < RR; ++r) s1 += sAcc[t][1+r]*sWr2[r*FF+f];
        float hpv = hpp[(size_t)n*FF+f];
        float b3 = br3[f];
        #pragma unroll
        for (int c = 0; c < 3; ++c){
            float s2 = b3*sAcc[t][16+c];
            #pragma unroll
            for (int r = 0; r < RR; ++r) s2 += sAcc[t][19+r*3+c]*sWr3[r*FF+f];
            float aggv = (vp[(size_t)n*48 + f*3 + c]*s1 + hpv*s2)/den;
            sVin[t][FF+f][c] = aggv;
            sVin[t][f][c] = sVA[t][f*3+c];
        }
    }
    __syncthreads();
    {
        float q0=0,q1=0,q2=0,k0=0,k1=0,k2=0;
        #pragma unroll
        for (int ff = 0; ff < 32; ++ff){
            int f = (ff + g) & 31;
            float w = sW1[g*32+f], u = sU1[g*32+f];
            float v0=sVin[t][f][0], v1=sVin[t][f][1], v2=sVin[t][f][2];
            q0+=w*v0;q1+=w*v1;q2+=w*v2;
            k0+=u*v0;k1+=u*v1;k2+=u*v2;
        }
        float dot=q0*k0+q1*k1+q2*k2;
        float ksq=k0*k0+k1*k1+k2*k2+EPSV;
        float s = dot>=0.f?0.f:dot/ksq;
        sVh[t][g][0]=q0-s*k0; sVh[t][g][1]=q1-s*k1; sVh[t][g][2]=q2-s*k2;
    }
    __syncthreads();
    if (g < 16){
        float o0=sVA[t][g*3+0], o1=sVA[t][g*3+1], o2=sVA[t][g*3+2];
        #pragma unroll
        for (int ff = 0; ff < 32; ++ff){
            int f = (ff + g) & 31;
            float w = sW2[g*32+f];
            o0 += w*sVh[t][f][0];
            o1 += w*sVh[t][f][1];
            o2 += w*sVh[t][f][2];
        }
        outV[(size_t)n*48 + g*3 + 0] = o0;
        outV[(size_t)n*48 + g*3 + 1] = o1;
        outV[(size_t)n*48 + g*3 + 2] = o2;
    }
}

extern "C" void kernel_launch(void* const* d_in, const int* in_sizes, int n_in,
                              void* d_out, int out_size, void* d_ws, size_t ws_size,
                              hipStream_t stream)
{
    const float* hA   = (const float*)d_in[0];
    const float* vA   = (const float*)d_in[1];
    const float* xA   = (const float*)d_in[2];
    const float* hB   = (const float*)d_in[3];
    const float* mask = (const float*)d_in[4];
    const int*   src  = (const int*)d_in[5];
    const int*   dst  = (const int*)d_in[6];
    const float* rbfk = (const float*)d_in[7];
    const float* Wr1  = (const float*)d_in[8];
    const float* br1  = (const float*)d_in[9];
    const float* Wr2  = (const float*)d_in[10];
    const float* br2  = (const float*)d_in[11];
    const float* Wr3  = (const float*)d_in[12];
    const float* br3  = (const float*)d_in[13];
    const float* vn1W = (const float*)d_in[14];
    const float* vn1U = (const float*)d_in[15];
    const float* vn2W = (const float*)d_in[16];
    const float* vn2U = (const float*)d_in[17];
    const float* vn3W = (const float*)d_in[18];
    const float* vn3U = (const float*)d_in[19];
    const float* phi1W= (const float*)d_in[20];
    const float* phi1b= (const float*)d_in[21];
    const float* phi2W= (const float*)d_in[22];
    const float* phi2b= (const float*)d_in[23];
    const float* phi3W= (const float*)d_in[24];
    const float* phi3b= (const float*)d_in[25];
    const float* Wq   = (const float*)d_in[26];
    const float* Wk   = (const float*)d_in[27];
    const float* Wv   = (const float*)d_in[28];
    const float* bv   = (const float*)d_in[29];
    const float* Wih  = (const float*)d_in[30];
    const float* Whh  = (const float*)d_in[31];
    const float* bih  = (const float*)d_in[32];
    const float* bhh  = (const float*)d_in[33];
    const float* W1   = (const float*)d_in[34];
    const float* U1   = (const float*)d_in[35];
    const float* W2   = (const float*)d_in[36];

    float* ws = (float*)d_ws;
    unsigned short* hpB = (unsigned short*)ws; ws += (size_t)NN*DD/2;
    unsigned short* attnB = (unsigned short*)ws; ws += ((size_t)NBLK*64*128)/2;
    unsigned short* hAB = (unsigned short*)ws; ws += ((size_t)NBLK*64*128)/2;
    float* hpp    = ws;  ws += (size_t)NN*FF;
    float* vp     = ws;  ws += (size_t)NN*FF*3;
    float* acc    = ws;  ws += (size_t)NN*64;
    unsigned short* pWih = (unsigned short*)ws; ws += (size_t)3*8*8*512/2;
    unsigned short* pWhh = (unsigned short*)ws; ws += (size_t)3*8*4*512/2;
    unsigned short* pWq  = (unsigned short*)ws; ws += (size_t)8*4*512/2;
    unsigned short* pKK  = (unsigned short*)ws; ws += (size_t)16*4*512/2;
    unsigned short* pVV  = (unsigned short*)ws; ws += (size_t)8*8*512/2;
    unsigned short* pPhi1= (unsigned short*)ws; ws += (size_t)8*5*512/2;
    unsigned short* pPhi2= (unsigned short*)ws; ws += (size_t)5*512/2;
    unsigned short* pPhi3= (unsigned short*)ws; ws += (size_t)4*512/2;
    unsigned short* pWr1 = (unsigned short*)ws; ws += (size_t)8*512/2;
    int* deg    = (int*)ws;  ws += NN;
    int* excl   = (int*)ws;  ws += NN;
    int* bsum   = (int*)ws;  ws += 256;
    int* startN = (int*)ws;  ws += NN+1;
    int* cursor = (int*)ws;  ws += NN;
    int* esrc   = (int*)ws;  ws += EE;

    float* outV = (float*)d_out;
    float* outH = (float*)d_out + (size_t)NN*FF*3;

    const int NB_SCAN = (NN + 255)/256;   // 196

    k_prep<<<512, 256, 0, stream>>>(Wih, Whh, Wq, phi1W, phi2W, phi3W, Wr1, br1,
                                    hB, Wk, Wv, bv,
                                    pWih, pWhh, pWq, pPhi1, pPhi2, pPhi3, pWr1,
                                    pKK, pVV, deg);
    k_hist<<<(EE+255)/256, 256, 0, stream>>>(dst, deg);
    k_scan1<<<NB_SCAN, 256, 0, stream>>>(deg, excl, bsum);
    k_scan23<<<NB_SCAN, 256, 0, stream>>>(excl, bsum, NB_SCAN, startN, cursor);
    k_scatter<<<(EE+255)/256, 256, 0, stream>>>(src, dst, cursor, esrc);
    k_node<<<NBLK, 512, 0, stream>>>(hA, vA, vn1W, vn1U, vn2W, vn2U, vn3W, vn3U,
                                     pPhi1, phi1b, pPhi2, phi2b, pPhi3, phi3b,
                                     hpB, hpp, vp, hAB);
    k_ga_attn<<<NGA + NBLK, 512, 0, stream>>>(startN, esrc, xA, rbfk, acc,
                                              hAB, pWq, pKK, pVV, mask, attnB);
    k_gru_mfma<<<NBLK, 512, 0, stream>>>(hAB, attnB, hpB, acc, pWr1,
                                         pWih, pWhh, bih, bhh, outH);
    k_vec<<<NN/8, 256, 0, stream>>>(vA, vp, hpp, acc, Wr2, br2, Wr3, br3, W1, U1, W2, outV);
}